// Round 16
// baseline (764.311 us; speedup 1.0000x reference)
//
#include <hip/hip_runtime.h>
#include <hip/hip_bf16.h>
#include <hip/hip_fp16.h>
#include <hip/hip_cooperative_groups.h>

namespace cg = cooperative_groups;

// ---------------------------------------------------------------------------
// GCN graph classifier: 3x GCNConv(128->128) + ReLU, mean-pool(64), linear(10)
// Strategy:
//   * R15: ALL graph preprocessing in ONE cooperative kernel (grid.sync
//     between phases): detect/init/wfrag -> hist -> blocksum -> scanb ->
//     fill -> scatter+xs. Was 7 launches (~50us incl gaps); scanb was a
//     1-block launch. Launch count 15 -> 9.
//   * R14: separate pool (R12 fused-pool 128-atomic flush serialized on hot
//     lines cross-XCD: 51us). Hot-line lesson x3 (R12 gcnt, R13, R14).
//   * R13: graph counts via binary search on sorted batch (zero atomics).
//   * R11: 8-aligned padded CSR; pad -> index N (zero row); agg = uniform
//     8-batch loop, uint4 = 8 packed u16 indices.
//   * R10: rows PRE-SCALED by dinv; agg = pure row sum * dinv[i].
//   * R9: one wave per node (R8 fusion cut gather TLP 16x -> regressed).
//   * R8: csr_src uint16; R7: MFMA GEMM w/ pre-packed W frags
//     (C/D col=lane&15,row=(lane>>4)*4+reg [HW-verified]); R6: fp16 rows.
// ---------------------------------------------------------------------------

#define HID 128
#define NGRAPH 64

typedef _Float16 half8v __attribute__((ext_vector_type(8)));
typedef float floatx4 __attribute__((ext_vector_type(4)));

__device__ __forceinline__ int idx_at(const void* p, long long i, int f64) {
    if (f64) return (int)((const long long*)p)[i];
    return ((const int*)p)[i];
}

__device__ __forceinline__ int wave_incl_scan(int v, int lane) {
#pragma unroll
    for (int off = 1; off < 64; off <<= 1) {
        int u = __shfl_up(v, off);
        if (lane >= off) v += u;
    }
    return v;
}

// R15: one cooperative kernel for all preprocessing.
__global__ __launch_bounds__(256) void preprocess_kernel(
    const void* __restrict__ ei, int* __restrict__ flag,
    int* __restrict__ counts, float* __restrict__ pooled,
    unsigned short* __restrict__ csr_src, int* __restrict__ rowstart,
    int* __restrict__ cursor, float* __restrict__ dinv,
    int* __restrict__ bsums, const float* __restrict__ x,
    __half2* __restrict__ xs, __half2* __restrict__ hsA,
    __half2* __restrict__ hsB, const float* __restrict__ W1,
    const float* __restrict__ W2, const float* __restrict__ W3,
    half8v* __restrict__ wf, int N, int E, int nCsr4, int n2) {
    cg::grid_group grid = cg::this_grid();
    const int tid = blockIdx.x * blockDim.x + threadIdx.x;
    const int nthreads = gridDim.x * blockDim.x;
    const int nb = (N + 255) >> 8;

    // ---- P0: detect int64 flag (block 0) + init + csr fill + zero rows +
    //          W fragment packing (weights need nothing upstream) ----
    if (blockIdx.x == 0) {
        __shared__ int cnt;
        if (threadIdx.x == 0) cnt = 0;
        __syncthreads();
        int z = 0;
        for (int k = threadIdx.x; k < 2048; k += 256)
            if (((const int*)ei)[2 * k + 1] == 0) z++;
        atomicAdd(&cnt, z);
        __syncthreads();
        if (threadIdx.x == 0) *flag = (cnt > 1024) ? 1 : 0;
    }
    for (int i = tid; i < N; i += nthreads) counts[i] = 0;
    for (int i = tid; i < NGRAPH * HID; i += nthreads) pooled[i] = 0.f;
    {
        unsigned fillv = (unsigned)N | ((unsigned)N << 16);
        uint4 fv = make_uint4(fillv, fillv, fillv, fillv);
        uint4* csr4 = (uint4*)csr_src;
        for (int j = tid; j < nCsr4; j += nthreads) csr4[j] = fv;
    }
    {
        __half2 z2 = __floats2half2_rn(0.f, 0.f);
        for (int t = tid; t < 192; t += nthreads) {
            if (t < 64) xs[(size_t)N * 64 + t] = z2;
            else if (t < 128) hsA[(size_t)N * 64 + (t - 64)] = z2;
            else hsB[(size_t)N * 64 + (t - 128)] = z2;
        }
    }
    for (int t = tid; t < 3 * 2048; t += nthreads) {
        int which = t >> 11;
        int tt = t & 2047;
        const float* W = which == 0 ? W1 : (which == 1 ? W2 : W3);
        int lane = tt & 63, nt2 = (tt >> 6) & 7, kblk = tt >> 9;
        int n = nt2 * 16 + (lane & 15);
        int kbase = kblk * 32 + (lane >> 4) * 8;
        half8v v;
#pragma unroll
        for (int j = 0; j < 8; ++j) v[j] = (_Float16)W[(size_t)(kbase + j) * 128 + n];
        wf[t] = v;
    }
    grid.sync();

    // ---- P1: degree histogram ----
    const int f64 = *flag;
    for (int e = tid; e < E; e += nthreads) {
        int d = idx_at(ei, (long long)E + e, f64);
        if ((unsigned)d < (unsigned)N) atomicAdd(&counts[d], 1);
    }
    grid.sync();

    // ---- P2: per-256-chunk padded sums ----
    {
        __shared__ int ws[4];
        for (int chunk = blockIdx.x; chunk < nb; chunk += gridDim.x) {
            int i = chunk * 256 + threadIdx.x;
            int v = (i < N) ? ((counts[i] + 7) & ~7) : 0;
            int lane = threadIdx.x & 63, w = threadIdx.x >> 6;
#pragma unroll
            for (int off = 32; off > 0; off >>= 1) v += __shfl_down(v, off);
            if (lane == 0) ws[w] = v;
            __syncthreads();
            if (threadIdx.x == 0) bsums[chunk] = ws[0] + ws[1] + ws[2] + ws[3];
            __syncthreads();
        }
    }
    grid.sync();

    // ---- P3: exclusive scan of chunk sums (block 0; nb <= 256) ----
    if (blockIdx.x == 0) {
        __shared__ int wsum[4];
        int t = threadIdx.x;
        int lane = t & 63, w = t >> 6;
        int v = (t < nb) ? bsums[t] : 0;
        int iv = wave_incl_scan(v, lane);
        if (lane == 63) wsum[w] = iv;
        __syncthreads();
        int add = 0;
        for (int k = 0; k < w; ++k) add += wsum[k];
        if (t < nb) bsums[t] = iv - v + add;
    }
    grid.sync();

    // ---- P4: rowstart/cursor/dinv ----
    {
        __shared__ int wsum2[4];
        for (int chunk = blockIdx.x; chunk < nb; chunk += gridDim.x) {
            int i = chunk * 256 + threadIdx.x;
            int c = (i < N) ? counts[i] : 0;
            int cp = (c + 7) & ~7;
            int lane = threadIdx.x & 63, w = threadIdx.x >> 6;
            int iv = wave_incl_scan(cp, lane);
            if (lane == 63) wsum2[w] = iv;
            __syncthreads();
            int add = bsums[chunk];
            for (int k = 0; k < w; ++k) add += wsum2[k];
            int excl = iv - cp + add;
            if (i < N) {
                rowstart[i] = excl;
                cursor[i] = excl;
                dinv[i] = rsqrtf((float)(c + 1));
                if (i == N - 1) rowstart[N] = excl + cp;
            }
            __syncthreads();
        }
    }
    grid.sync();

    // ---- P5: CSR scatter + pre-scaled fp16 xs (needs dinv) ----
    for (int e = tid; e < E; e += nthreads) {
        int s = idx_at(ei, e, f64);
        int d = idx_at(ei, (long long)E + e, f64);
        if ((unsigned)s < (unsigned)N && (unsigned)d < (unsigned)N) {
            int pos = atomicAdd(&cursor[d], 1);
            csr_src[pos] = (unsigned short)s;
        }
    }
    for (int i = tid; i < n2; i += nthreads) {
        float dv = dinv[i >> 6];
        float2 v = ((const float2*)x)[i];
        xs[i] = __floats2half2_rn(dv * v.x, dv * v.y);
    }
}

// agg[i] = dinv[i] * ( xs[i] + sum_e xs[src_e] )   (rows pre-scaled, R10)
// ONE WAVE PER NODE. R11: padded CSR -> single uniform 8-batch loop; indices
// loaded 8-at-a-time as one uint4; pad slots hit the zero row (L1-resident).
__global__ __launch_bounds__(256) void agg_kernel(const __half2* __restrict__ xs,
                                                  const int* __restrict__ rowstart,
                                                  const unsigned short* __restrict__ csr_src,
                                                  const float* __restrict__ dinv,
                                                  __half2* __restrict__ out, int N) {
    int wid = (blockIdx.x * blockDim.x + threadIdx.x) >> 6;
    int lane = threadIdx.x & 63;
    if (wid >= N) return;
    float di = dinv[wid];
    float2 s0 = __half22float2(xs[(size_t)wid * 64 + lane]);
    float accx = s0.x, accy = s0.y;
    float bccx = 0.f, bccy = 0.f;
    int e0 = rowstart[wid], e1 = rowstart[wid + 1];
    for (int e = e0; e < e1; e += 8) {
        uint4 q = *(const uint4*)(csr_src + e);   // 8 packed uint16 indices
        int s0i = q.x & 0xffff, s1i = q.x >> 16;
        int s2i = q.y & 0xffff, s3i = q.y >> 16;
        int s4i = q.z & 0xffff, s5i = q.z >> 16;
        int s6i = q.w & 0xffff, s7i = q.w >> 16;
        __half2 v0 = xs[(size_t)s0i * 64 + lane];
        __half2 v1 = xs[(size_t)s1i * 64 + lane];
        __half2 v2 = xs[(size_t)s2i * 64 + lane];
        __half2 v3 = xs[(size_t)s3i * 64 + lane];
        __half2 v4 = xs[(size_t)s4i * 64 + lane];
        __half2 v5 = xs[(size_t)s5i * 64 + lane];
        __half2 v6 = xs[(size_t)s6i * 64 + lane];
        __half2 v7 = xs[(size_t)s7i * 64 + lane];
        float2 f0 = __half22float2(v0), f1 = __half22float2(v1);
        float2 f2 = __half22float2(v2), f3 = __half22float2(v3);
        float2 f4 = __half22float2(v4), f5 = __half22float2(v5);
        float2 f6 = __half22float2(v6), f7 = __half22float2(v7);
        accx += f0.x + f2.x; accy += f0.y + f2.y;
        bccx += f1.x + f3.x; bccy += f1.y + f3.y;
        accx += f4.x + f6.x; accy += f4.y + f6.y;
        bccx += f5.x + f7.x; bccy += f5.y + f7.y;
    }
    out[(size_t)wid * 64 + lane] = __floats2half2_rn(di * (accx + bccx),
                                                     di * (accy + bccy));
}

// h = relu(A @ W + b) via v_mfma_f32_16x16x32_f16. A:[M][128] fp16, W frags
// L2-resident. No LDS, no barriers. Wave owns 16 rows x 128 cols (32 MFMAs).
// SCALED (layers 1,2): O16 = dinv*relu(...). !SCALED (layer 3): plain relu.
template <bool SCALED>
__global__ __launch_bounds__(256) void gemm_mfma(const __half2* __restrict__ A16,
                                                 const half8v* __restrict__ wf,
                                                 const float* __restrict__ bias,
                                                 const float* __restrict__ dinv,
                                                 __half2* __restrict__ O16, int M) {
    int wid = threadIdx.x >> 6, lane = threadIdx.x & 63;
    int rowTile = blockIdx.x * 64 + wid * 16;
    int hi = lane >> 4;
    int arow = rowTile + (lane & 15);
    if (arow >= M) arow = M - 1;  // clamp; outputs guarded below
    const half8v* Arow = (const half8v*)((const _Float16*)A16 + (size_t)arow * 128);

    floatx4 acc[8];
#pragma unroll
    for (int nt = 0; nt < 8; ++nt) acc[nt] = (floatx4){0.f, 0.f, 0.f, 0.f};

#pragma unroll
    for (int kb = 0; kb < 4; ++kb) {
        half8v a = Arow[kb * 4 + hi];
#pragma unroll
        for (int nt = 0; nt < 8; ++nt) {
            half8v w = wf[(kb * 8 + nt) * 64 + lane];
            acc[nt] = __builtin_amdgcn_mfma_f32_16x16x32_f16(a, w, acc[nt], 0, 0, 0);
        }
    }

    // C/D: col = lane&15, row = (lane>>4)*4 + reg   [HW-verified]
    int ocol_lo = lane & 15;
    int orow0 = rowTile + hi * 4;
    float dv[4];
#pragma unroll
    for (int r = 0; r < 4; ++r) {
        int orow = orow0 + r;
        dv[r] = (SCALED && orow < M) ? dinv[orow] : 1.0f;
    }
#pragma unroll
    for (int nt = 0; nt < 8; ++nt) {
        int col = nt * 16 + ocol_lo;
        float b = bias[col];
#pragma unroll
        for (int r = 0; r < 4; ++r) {
            int orow = orow0 + r;
            if (orow < M) {
                float v = fmaxf(acc[nt][r] + b, 0.f);
                if (SCALED) v *= dv[r];
                ((_Float16*)O16)[(size_t)orow * 128 + col] = (_Float16)v;
            }
        }
    }
}

// batch is sorted: one WAVE per 16-node chunk, half2/lane (128 features),
// fp32 accumulate, atomic flush at graph boundaries (R1/R9). Sums only —
// counts come from binary search in final (R13).
#define POOL_CHUNK 16
__global__ __launch_bounds__(256) void pool_kernel(const __half2* __restrict__ h,
                                                   const void* __restrict__ batch,
                                                   const int* __restrict__ flag,
                                                   float* __restrict__ pooled, int N) {
    int wid = (blockIdx.x * blockDim.x + threadIdx.x) >> 6;
    int lane = threadIdx.x & 63;
    int n0 = wid * POOL_CHUNK;
    if (n0 >= N) return;
    int n1 = n0 + POOL_CHUNK; if (n1 > N) n1 = N;
    int f64 = *flag;
    int g = idx_at(batch, n0, f64);
    float ax = 0.f, ay = 0.f;
    for (int n = n0; n < n1; ++n) {
        int gn = idx_at(batch, n, f64);
        if (gn != g) {
            if ((unsigned)g < (unsigned)NGRAPH) {
                atomicAdd(&pooled[g * HID + 2 * lane], ax);
                atomicAdd(&pooled[g * HID + 2 * lane + 1], ay);
            }
            ax = ay = 0.f; g = gn;
        }
        float2 v = __half22float2(h[(size_t)n * 64 + lane]);
        ax += v.x; ay += v.y;
    }
    if ((unsigned)g < (unsigned)NGRAPH) {
        atomicAdd(&pooled[g * HID + 2 * lane], ax);
        atomicAdd(&pooled[g * HID + 2 * lane + 1], ay);
    }
}

// R13: per-graph node count via binary search on sorted batch (no atomics).
__global__ __launch_bounds__(128) void final_kernel(const float* __restrict__ pooled,
                                                    const void* __restrict__ batch,
                                                    const int* __restrict__ flag,
                                                    const float* __restrict__ Wl,
                                                    const float* __restrict__ bl,
                                                    float* __restrict__ out, int N) {
    int o = blockIdx.x * blockDim.x + threadIdx.x;
    if (o >= NGRAPH * 10) return;
    int g = o / 10, c = o % 10;
    int f64 = *flag;
    auto lb = [&](int val) {
        int lo = 0, hi = N;
        while (lo < hi) {
            int mid = (lo + hi) >> 1;
            if (idx_at(batch, mid, f64) < val) lo = mid + 1; else hi = mid;
        }
        return lo;
    };
    int cnt = lb(g + 1) - lb(g);
    float inv = 1.0f / fmaxf((float)cnt, 1.0f);
    float acc = 0.f;
    for (int k = 0; k < HID; ++k)
        acc = fmaf(pooled[g * HID + k], Wl[k * 10 + c], acc);
    out[o] = acc * inv + bl[c];
}

extern "C" void kernel_launch(void* const* d_in, const int* in_sizes, int n_in,
                              void* d_out, int out_size, void* d_ws, size_t ws_size,
                              hipStream_t stream) {
    const float* x   = (const float*)d_in[0];
    const void* ei   = d_in[1];
    const void* bat  = d_in[2];
    const float* W1  = (const float*)d_in[3];
    const float* b1  = (const float*)d_in[4];
    const float* W2  = (const float*)d_in[5];
    const float* b2  = (const float*)d_in[6];
    const float* W3  = (const float*)d_in[7];
    const float* b3  = (const float*)d_in[8];
    const float* Wl  = (const float*)d_in[9];
    const float* bl  = (const float*)d_in[10];
    float* out = (float*)d_out;

    const int N = in_sizes[0] / HID;   // 50000 (< 65536: csr_src is uint16)
    const int E = in_sizes[1] / 2;     // 600000
    const int EPAD = (E + 7 * N + 7) & ~7;   // padded-CSR capacity

    char* w = (char*)d_ws;
    size_t off = 0;
    auto carve = [&](size_t bytes) -> void* {
        void* p = w + off;
        off = (off + bytes + 255) & ~(size_t)255;
        return p;
    };
    __half2* xs       = (__half2*)carve((size_t)(N + 1) * HID * 2); // dinv*x (+zero row)
    __half2* aggB16   = (__half2*)carve((size_t)N * HID * 2);       // agg out (GEMM A)
    __half2* hsA      = (__half2*)carve((size_t)(N + 1) * HID * 2); // dinv*h1 (+zero) / h3
    __half2* hsB      = (__half2*)carve((size_t)(N + 1) * HID * 2); // dinv*h2 (+zero)
    int*     counts   = (int*)carve((size_t)N * 4);
    int*     rowstart = (int*)carve((size_t)(N + 1) * 4);
    int*     cursor   = (int*)carve((size_t)N * 4);
    float*   dinv     = (float*)carve((size_t)N * 4);
    unsigned short* csr_src = (unsigned short*)carve((size_t)EPAD * 2);
    float*   pooled   = (float*)carve((size_t)NGRAPH * HID * 4);
    half8v*  wf       = (half8v*)carve(3 * 2048 * 16);              // 3 packed W
    int*     bsums    = (int*)carve(1024);
    int*     flag     = (int*)carve(256);

    int nCsr4 = EPAD / 8;
    int n2 = N * HID / 2;
    int N_ = N, E_ = E;

    // R15: single cooperative preprocessing kernel (phases sync via grid.sync)
    void* args[] = { (void*)&ei, (void*)&flag, (void*)&counts, (void*)&pooled,
                     (void*)&csr_src, (void*)&rowstart, (void*)&cursor,
                     (void*)&dinv, (void*)&bsums, (void*)&x, (void*)&xs,
                     (void*)&hsA, (void*)&hsB, (void*)&W1, (void*)&W2,
                     (void*)&W3, (void*)&wf, (void*)&N_, (void*)&E_,
                     (void*)&nCsr4, (void*)&n2 };
    hipLaunchCooperativeKernel((void*)preprocess_kernel, dim3(1024), dim3(256),
                               args, 0, stream);

    int aggBlocks  = (N + 3) / 4;        // one wave per node, 4 waves/block
    int gemmBlocks = (N + 63) / 64;      // 64 rows/block (4 waves x 16 rows)

    // layer 1
    agg_kernel<<<aggBlocks, 256, 0, stream>>>(xs, rowstart, csr_src, dinv, aggB16, N);
    gemm_mfma<true><<<gemmBlocks, 256, 0, stream>>>(aggB16, wf, b1, dinv, hsA, N);
    // layer 2
    agg_kernel<<<aggBlocks, 256, 0, stream>>>(hsA, rowstart, csr_src, dinv, aggB16, N);
    gemm_mfma<true><<<gemmBlocks, 256, 0, stream>>>(aggB16, wf + 2048, b2, dinv, hsB, N);
    // layer 3 (plain relu h3 into hsA rows < N; zero row untouched)
    agg_kernel<<<aggBlocks, 256, 0, stream>>>(hsB, rowstart, csr_src, dinv, aggB16, N);
    gemm_mfma<false><<<gemmBlocks, 256, 0, stream>>>(aggB16, wf + 4096, b3, dinv, hsA, N);

    // mean pool (fp16 h3) + final linear (binary-searched counts)
    int poolWaves = (N + POOL_CHUNK - 1) / POOL_CHUNK;
    int poolBlocks = (poolWaves + 3) / 4;
    pool_kernel<<<poolBlocks, 256, 0, stream>>>(hsA, bat, flag, pooled, N);
    final_kernel<<<5, 128, 0, stream>>>(pooled, bat, flag, Wl, bl, out, N);
}

// Round 17
// 222.578 us; speedup vs baseline: 3.4339x; 3.4339x over previous
//
#include <hip/hip_runtime.h>
#include <hip/hip_bf16.h>
#include <hip/hip_fp16.h>

// ---------------------------------------------------------------------------
// GCN graph classifier: 3x GCNConv(128->128) + ReLU, mean-pool(64), linear(10)
// Strategy:
//   * R16: REVERTED R15's cooperative mega-kernel — grid.sync() spins 1024
//     blocks on one device-scope cache line cross-XCD (~100us/sync, 612us
//     total). Hot-line lesson x4: on MI355X, separate captured launches are
//     the CHEAP sync primitive. Back to the 7-launch preprocessing chain.
//   * R14: separate pool (R12 fused-pool 128-atomic flush serialized on hot
//     lines cross-XCD: 51us). R13: graph counts via binary search (0 atomics).
//   * R11: 8-aligned padded CSR; pad -> index N (zero row); agg = uniform
//     8-batch loop, uint4 = 8 packed u16 indices.
//   * R10: rows PRE-SCALED by dinv; agg = pure row sum * dinv[i].
//   * R9: one wave per node (R8 fusion cut gather TLP 16x -> regressed).
//   * R8: csr_src uint16; R7: MFMA GEMM w/ pre-packed W frags
//     (C/D col=lane&15,row=(lane>>4)*4+reg [HW-verified]); R6: fp16 rows;
//     R2: 3-kernel parallel scan.
//   * R16 micro: POOL_CHUNK 16->8 (2x pool waves; latency-bound reads).
// ---------------------------------------------------------------------------

#define HID 128
#define NGRAPH 64

typedef _Float16 half8v __attribute__((ext_vector_type(8)));
typedef float floatx4 __attribute__((ext_vector_type(4)));

__device__ __forceinline__ int idx_at(const void* p, long long i, int f64) {
    if (f64) return (int)((const long long*)p)[i];
    return ((const int*)p)[i];
}

// init counts/pooled + fill padded csr_src with N (zero-row index);
// block 0 also detects int64-vs-int32 edge_index (odd 32-bit words all zero).
__global__ void init_kernel(const int* __restrict__ ei, int* __restrict__ flag,
                            int* __restrict__ counts, float* __restrict__ pooled,
                            uint4* __restrict__ csr4, int N, int nCsr4) {
    int i = blockIdx.x * blockDim.x + threadIdx.x;
    int stride = gridDim.x * blockDim.x;
    if (i < N) counts[i] = 0;
    if (i < NGRAPH * HID) pooled[i] = 0.f;
    unsigned fillv = (unsigned)N | ((unsigned)N << 16);
    uint4 fv = make_uint4(fillv, fillv, fillv, fillv);
    for (int j = i; j < nCsr4; j += stride) csr4[j] = fv;
    if (blockIdx.x == 0) {
        __shared__ int cnt;
        if (threadIdx.x == 0) cnt = 0;
        __syncthreads();
        int z = 0;
        for (int k = threadIdx.x; k < 2048; k += 256)
            if (ei[2 * k + 1] == 0) z++;
        atomicAdd(&cnt, z);
        __syncthreads();
        if (threadIdx.x == 0) *flag = (cnt > 1024) ? 1 : 0;
    }
}

__global__ void hist_kernel(const void* __restrict__ ei, const int* __restrict__ flag,
                            int* __restrict__ counts, int E, int N) {
    int e = blockIdx.x * blockDim.x + threadIdx.x;
    if (e >= E) return;
    int f64 = *flag;
    int d = idx_at(ei, (long long)E + e, f64);
    if ((unsigned)d < (unsigned)N) atomicAdd(&counts[d], 1);
}

__device__ __forceinline__ int wave_incl_scan(int v, int lane) {
#pragma unroll
    for (int off = 1; off < 64; off <<= 1) {
        int u = __shfl_up(v, off);
        if (lane >= off) v += u;
    }
    return v;
}

// ---- 3-kernel parallel exclusive scan over PADDED counts (R2/R11) ----
__global__ __launch_bounds__(256) void blocksum_kernel(const int* __restrict__ counts,
                                                       int* __restrict__ bsums, int N) {
    int i = blockIdx.x * 256 + threadIdx.x;
    int v = (i < N) ? ((counts[i] + 7) & ~7) : 0;  // padded to 8
    int lane = threadIdx.x & 63, w = threadIdx.x >> 6;
#pragma unroll
    for (int off = 32; off > 0; off >>= 1) v += __shfl_down(v, off);
    __shared__ int ws[4];
    if (lane == 0) ws[w] = v;
    __syncthreads();
    if (threadIdx.x == 0) bsums[blockIdx.x] = ws[0] + ws[1] + ws[2] + ws[3];
}

__global__ __launch_bounds__(256) void scanb_kernel(int* __restrict__ bsums, int nb) {
    int t = threadIdx.x;
    int lane = t & 63, w = t >> 6;
    int v = (t < nb) ? bsums[t] : 0;
    int iv = wave_incl_scan(v, lane);
    __shared__ int wsum[4];
    if (lane == 63) wsum[w] = iv;
    __syncthreads();
    int add = 0;
    for (int k = 0; k < w; ++k) add += wsum[k];
    if (t < nb) bsums[t] = iv - v + add;  // exclusive
}

__global__ __launch_bounds__(256) void fill_kernel(const int* __restrict__ counts,
                                                   const int* __restrict__ bsums,
                                                   int* __restrict__ rowstart,
                                                   int* __restrict__ cursor,
                                                   float* __restrict__ dinv, int N) {
    int i = blockIdx.x * 256 + threadIdx.x;
    int c = (i < N) ? counts[i] : 0;
    int cp = (c + 7) & ~7;                        // padded
    int lane = threadIdx.x & 63, w = threadIdx.x >> 6;
    int iv = wave_incl_scan(cp, lane);
    __shared__ int wsum[4];
    if (lane == 63) wsum[w] = iv;
    __syncthreads();
    int add = bsums[blockIdx.x];
    for (int k = 0; k < w; ++k) add += wsum[k];
    int excl = iv - cp + add;
    if (i < N) {
        rowstart[i] = excl;
        cursor[i] = excl;
        dinv[i] = rsqrtf((float)(c + 1));
        if (i == N - 1) rowstart[N] = excl + cp;
    }
}

// R5: stores ONLY csr_src; R8: uint16 (requires N < 65536; here N=50000)
__global__ void scatter_kernel(const void* __restrict__ ei, const int* __restrict__ flag,
                               int* __restrict__ cursor,
                               unsigned short* __restrict__ csr_src, int E, int N) {
    int e = blockIdx.x * blockDim.x + threadIdx.x;
    if (e >= E) return;
    int f64 = *flag;
    int s = idx_at(ei, e, f64);
    int d = idx_at(ei, (long long)E + e, f64);
    if ((unsigned)s >= (unsigned)N || (unsigned)d >= (unsigned)N) return;
    int pos = atomicAdd(&cursor[d], 1);
    csr_src[pos] = (unsigned short)s;
}

// R10/R11 merged prep: blocks [0,24): pack 3x W into fragment-ordered fp16;
// block 24: zero row N of xs/hsA/hsB (gather target of pad indices);
// blocks [25,..): xs = dinv * x in fp16 (pre-scaled layer-1 gather source).
__global__ __launch_bounds__(256) void prep_kernel(const float* __restrict__ x,
                                                   const float* __restrict__ dinv,
                                                   __half2* __restrict__ xs,
                                                   __half2* __restrict__ hsA,
                                                   __half2* __restrict__ hsB,
                                                   const float* __restrict__ W1,
                                                   const float* __restrict__ W2,
                                                   const float* __restrict__ W3,
                                                   half8v* __restrict__ wf,
                                                   int N, int n2) {
    if (blockIdx.x < 24) {
        int which = blockIdx.x >> 3;
        const float* W = which == 0 ? W1 : (which == 1 ? W2 : W3);
        int t = (blockIdx.x & 7) * 256 + threadIdx.x;  // 0..2047
        int lane = t & 63;
        int nt = (t >> 6) & 7;
        int kblk = t >> 9;
        int n = nt * 16 + (lane & 15);
        int kbase = kblk * 32 + (lane >> 4) * 8;
        half8v v;
#pragma unroll
        for (int j = 0; j < 8; ++j) v[j] = (_Float16)W[(size_t)(kbase + j) * 128 + n];
        wf[which * 2048 + t] = v;
    } else if (blockIdx.x == 24) {
        // zero row N of the three gather sources (64 half2 each)
        int t = threadIdx.x;
        __half2 z = __floats2half2_rn(0.f, 0.f);
        if (t < 64) xs[(size_t)N * 64 + t] = z;
        else if (t < 128) hsA[(size_t)N * 64 + (t - 64)] = z;
        else if (t < 192) hsB[(size_t)N * 64 + (t - 128)] = z;
    } else {
        int i = (blockIdx.x - 25) * 256 + threadIdx.x;
        if (i >= n2) return;
        float dv = dinv[i >> 6];
        float2 v = ((const float2*)x)[i];
        xs[i] = __floats2half2_rn(dv * v.x, dv * v.y);
    }
}

// agg[i] = dinv[i] * ( xs[i] + sum_e xs[src_e] )   (rows pre-scaled, R10)
// ONE WAVE PER NODE. R11: padded CSR -> single uniform 8-batch loop; indices
// loaded 8-at-a-time as one uint4; pad slots hit the zero row (L1-resident).
__global__ __launch_bounds__(256) void agg_kernel(const __half2* __restrict__ xs,
                                                  const int* __restrict__ rowstart,
                                                  const unsigned short* __restrict__ csr_src,
                                                  const float* __restrict__ dinv,
                                                  __half2* __restrict__ out, int N) {
    int wid = (blockIdx.x * blockDim.x + threadIdx.x) >> 6;
    int lane = threadIdx.x & 63;
    if (wid >= N) return;
    float di = dinv[wid];
    float2 s0 = __half22float2(xs[(size_t)wid * 64 + lane]);
    float accx = s0.x, accy = s0.y;
    float bccx = 0.f, bccy = 0.f;
    int e0 = rowstart[wid], e1 = rowstart[wid + 1];
    for (int e = e0; e < e1; e += 8) {
        uint4 q = *(const uint4*)(csr_src + e);   // 8 packed uint16 indices
        int s0i = q.x & 0xffff, s1i = q.x >> 16;
        int s2i = q.y & 0xffff, s3i = q.y >> 16;
        int s4i = q.z & 0xffff, s5i = q.z >> 16;
        int s6i = q.w & 0xffff, s7i = q.w >> 16;
        __half2 v0 = xs[(size_t)s0i * 64 + lane];
        __half2 v1 = xs[(size_t)s1i * 64 + lane];
        __half2 v2 = xs[(size_t)s2i * 64 + lane];
        __half2 v3 = xs[(size_t)s3i * 64 + lane];
        __half2 v4 = xs[(size_t)s4i * 64 + lane];
        __half2 v5 = xs[(size_t)s5i * 64 + lane];
        __half2 v6 = xs[(size_t)s6i * 64 + lane];
        __half2 v7 = xs[(size_t)s7i * 64 + lane];
        float2 f0 = __half22float2(v0), f1 = __half22float2(v1);
        float2 f2 = __half22float2(v2), f3 = __half22float2(v3);
        float2 f4 = __half22float2(v4), f5 = __half22float2(v5);
        float2 f6 = __half22float2(v6), f7 = __half22float2(v7);
        accx += f0.x + f2.x; accy += f0.y + f2.y;
        bccx += f1.x + f3.x; bccy += f1.y + f3.y;
        accx += f4.x + f6.x; accy += f4.y + f6.y;
        bccx += f5.x + f7.x; bccy += f5.y + f7.y;
    }
    out[(size_t)wid * 64 + lane] = __floats2half2_rn(di * (accx + bccx),
                                                     di * (accy + bccy));
}

// h = relu(A @ W + b) via v_mfma_f32_16x16x32_f16. A:[M][128] fp16, W frags
// L2-resident. No LDS, no barriers. Wave owns 16 rows x 128 cols (32 MFMAs).
// SCALED (layers 1,2): O16 = dinv*relu(...). !SCALED (layer 3): plain relu.
template <bool SCALED>
__global__ __launch_bounds__(256) void gemm_mfma(const __half2* __restrict__ A16,
                                                 const half8v* __restrict__ wf,
                                                 const float* __restrict__ bias,
                                                 const float* __restrict__ dinv,
                                                 __half2* __restrict__ O16, int M) {
    int wid = threadIdx.x >> 6, lane = threadIdx.x & 63;
    int rowTile = blockIdx.x * 64 + wid * 16;
    int hi = lane >> 4;
    int arow = rowTile + (lane & 15);
    if (arow >= M) arow = M - 1;  // clamp; outputs guarded below
    const half8v* Arow = (const half8v*)((const _Float16*)A16 + (size_t)arow * 128);

    floatx4 acc[8];
#pragma unroll
    for (int nt = 0; nt < 8; ++nt) acc[nt] = (floatx4){0.f, 0.f, 0.f, 0.f};

#pragma unroll
    for (int kb = 0; kb < 4; ++kb) {
        half8v a = Arow[kb * 4 + hi];
#pragma unroll
        for (int nt = 0; nt < 8; ++nt) {
            half8v w = wf[(kb * 8 + nt) * 64 + lane];
            acc[nt] = __builtin_amdgcn_mfma_f32_16x16x32_f16(a, w, acc[nt], 0, 0, 0);
        }
    }

    // C/D: col = lane&15, row = (lane>>4)*4 + reg   [HW-verified]
    int ocol_lo = lane & 15;
    int orow0 = rowTile + hi * 4;
    float dv[4];
#pragma unroll
    for (int r = 0; r < 4; ++r) {
        int orow = orow0 + r;
        dv[r] = (SCALED && orow < M) ? dinv[orow] : 1.0f;
    }
#pragma unroll
    for (int nt = 0; nt < 8; ++nt) {
        int col = nt * 16 + ocol_lo;
        float b = bias[col];
#pragma unroll
        for (int r = 0; r < 4; ++r) {
            int orow = orow0 + r;
            if (orow < M) {
                float v = fmaxf(acc[nt][r] + b, 0.f);
                if (SCALED) v *= dv[r];
                ((_Float16*)O16)[(size_t)orow * 128 + col] = (_Float16)v;
            }
        }
    }
}

// batch is sorted: one WAVE per 8-node chunk (R16: was 16; more TLP),
// half2/lane (128 features), fp32 accumulate, atomic flush at graph
// boundaries. Sums only — counts via binary search in final (R13).
#define POOL_CHUNK 8
__global__ __launch_bounds__(256) void pool_kernel(const __half2* __restrict__ h,
                                                   const void* __restrict__ batch,
                                                   const int* __restrict__ flag,
                                                   float* __restrict__ pooled, int N) {
    int wid = (blockIdx.x * blockDim.x + threadIdx.x) >> 6;
    int lane = threadIdx.x & 63;
    int n0 = wid * POOL_CHUNK;
    if (n0 >= N) return;
    int n1 = n0 + POOL_CHUNK; if (n1 > N) n1 = N;
    int f64 = *flag;
    int g = idx_at(batch, n0, f64);
    float ax = 0.f, ay = 0.f;
    for (int n = n0; n < n1; ++n) {
        int gn = idx_at(batch, n, f64);
        if (gn != g) {
            if ((unsigned)g < (unsigned)NGRAPH) {
                atomicAdd(&pooled[g * HID + 2 * lane], ax);
                atomicAdd(&pooled[g * HID + 2 * lane + 1], ay);
            }
            ax = ay = 0.f; g = gn;
        }
        float2 v = __half22float2(h[(size_t)n * 64 + lane]);
        ax += v.x; ay += v.y;
    }
    if ((unsigned)g < (unsigned)NGRAPH) {
        atomicAdd(&pooled[g * HID + 2 * lane], ax);
        atomicAdd(&pooled[g * HID + 2 * lane + 1], ay);
    }
}

// R13: per-graph node count via binary search on sorted batch (no atomics).
__global__ __launch_bounds__(128) void final_kernel(const float* __restrict__ pooled,
                                                    const void* __restrict__ batch,
                                                    const int* __restrict__ flag,
                                                    const float* __restrict__ Wl,
                                                    const float* __restrict__ bl,
                                                    float* __restrict__ out, int N) {
    int o = blockIdx.x * blockDim.x + threadIdx.x;
    if (o >= NGRAPH * 10) return;
    int g = o / 10, c = o % 10;
    int f64 = *flag;
    auto lb = [&](int val) {
        int lo = 0, hi = N;
        while (lo < hi) {
            int mid = (lo + hi) >> 1;
            if (idx_at(batch, mid, f64) < val) lo = mid + 1; else hi = mid;
        }
        return lo;
    };
    int cnt = lb(g + 1) - lb(g);
    float inv = 1.0f / fmaxf((float)cnt, 1.0f);
    float acc = 0.f;
    for (int k = 0; k < HID; ++k)
        acc = fmaf(pooled[g * HID + k], Wl[k * 10 + c], acc);
    out[o] = acc * inv + bl[c];
}

extern "C" void kernel_launch(void* const* d_in, const int* in_sizes, int n_in,
                              void* d_out, int out_size, void* d_ws, size_t ws_size,
                              hipStream_t stream) {
    const float* x   = (const float*)d_in[0];
    const void* ei   = d_in[1];
    const void* bat  = d_in[2];
    const float* W1  = (const float*)d_in[3];
    const float* b1  = (const float*)d_in[4];
    const float* W2  = (const float*)d_in[5];
    const float* b2  = (const float*)d_in[6];
    const float* W3  = (const float*)d_in[7];
    const float* b3  = (const float*)d_in[8];
    const float* Wl  = (const float*)d_in[9];
    const float* bl  = (const float*)d_in[10];
    float* out = (float*)d_out;

    const int N = in_sizes[0] / HID;   // 50000 (< 65536: csr_src is uint16)
    const int E = in_sizes[1] / 2;     // 600000
    const int EPAD = (E + 7 * N + 7) & ~7;   // padded-CSR capacity

    char* w = (char*)d_ws;
    size_t off = 0;
    auto carve = [&](size_t bytes) -> void* {
        void* p = w + off;
        off = (off + bytes + 255) & ~(size_t)255;
        return p;
    };
    __half2* xs       = (__half2*)carve((size_t)(N + 1) * HID * 2); // dinv*x (+zero row)
    __half2* aggB16   = (__half2*)carve((size_t)N * HID * 2);       // agg out (GEMM A)
    __half2* hsA      = (__half2*)carve((size_t)(N + 1) * HID * 2); // dinv*h1 (+zero) / h3
    __half2* hsB      = (__half2*)carve((size_t)(N + 1) * HID * 2); // dinv*h2 (+zero)
    int*     counts   = (int*)carve((size_t)N * 4);
    int*     rowstart = (int*)carve((size_t)(N + 1) * 4);
    int*     cursor   = (int*)carve((size_t)N * 4);
    float*   dinv     = (float*)carve((size_t)N * 4);
    unsigned short* csr_src = (unsigned short*)carve((size_t)EPAD * 2);
    float*   pooled   = (float*)carve((size_t)NGRAPH * HID * 4);
    half8v*  wf       = (half8v*)carve(3 * 2048 * 16);              // 3 packed W
    int*     bsums    = (int*)carve(1024);
    int*     flag     = (int*)carve(256);

    const int nb = (N + 255) / 256;
    const int n2 = N * HID / 2;

    // graph preprocessing (once; shared by all 3 layers)
    init_kernel<<<nb, 256, 0, stream>>>((const int*)ei, flag, counts, pooled,
                                        (uint4*)csr_src, N, EPAD / 8);
    hist_kernel<<<(E + 255) / 256, 256, 0, stream>>>(ei, flag, counts, E, N);
    blocksum_kernel<<<nb, 256, 0, stream>>>(counts, bsums, N);
    scanb_kernel<<<1, 256, 0, stream>>>(bsums, nb);
    fill_kernel<<<nb, 256, 0, stream>>>(counts, bsums, rowstart, cursor, dinv, N);
    scatter_kernel<<<(E + 255) / 256, 256, 0, stream>>>(ei, flag, cursor, csr_src, E, N);
    prep_kernel<<<25 + (n2 + 255) / 256, 256, 0, stream>>>(x, dinv, xs, hsA, hsB,
                                                           W1, W2, W3, wf, N, n2);

    int aggBlocks  = (N + 3) / 4;        // one wave per node, 4 waves/block
    int gemmBlocks = (N + 63) / 64;      // 64 rows/block (4 waves x 16 rows)

    // layer 1
    agg_kernel<<<aggBlocks, 256, 0, stream>>>(xs, rowstart, csr_src, dinv, aggB16, N);
    gemm_mfma<true><<<gemmBlocks, 256, 0, stream>>>(aggB16, wf, b1, dinv, hsA, N);
    // layer 2
    agg_kernel<<<aggBlocks, 256, 0, stream>>>(hsA, rowstart, csr_src, dinv, aggB16, N);
    gemm_mfma<true><<<gemmBlocks, 256, 0, stream>>>(aggB16, wf + 2048, b2, dinv, hsB, N);
    // layer 3 (plain relu h3 into hsA rows < N; zero row untouched)
    agg_kernel<<<aggBlocks, 256, 0, stream>>>(hsB, rowstart, csr_src, dinv, aggB16, N);
    gemm_mfma<false><<<gemmBlocks, 256, 0, stream>>>(aggB16, wf + 4096, b3, dinv, hsA, N);

    // mean pool (fp16 h3) + final linear (binary-searched counts)
    int poolWaves = (N + POOL_CHUNK - 1) / POOL_CHUNK;
    int poolBlocks = (poolWaves + 3) / 4;
    pool_kernel<<<poolBlocks, 256, 0, stream>>>(hsA, bat, flag, pooled, N);
    final_kernel<<<5, 128, 0, stream>>>(pooled, bat, flag, Wl, bl, out, N);
}

// Round 18
// 204.452 us; speedup vs baseline: 3.7383x; 1.0887x over previous
//
#include <hip/hip_runtime.h>
#include <hip/hip_bf16.h>
#include <hip/hip_fp16.h>

// ---------------------------------------------------------------------------
// GCN graph classifier: 3x GCNConv(128->128) + ReLU, mean-pool(64), linear(10)
// Strategy:
//   * R17: FP8 (e4m3, HW cvt) GATHER ROWS (128B; was fp16 256B). agg is
//     byte-bound on the L2-miss/L3 random path (R6: fp16 gave 1.55x; R4: MLP
//     null; FETCH 75MB @ 2.4TB/s). Encode/decode both via HW cvt_pk ops ->
//     roundtrip format-consistent. agg acc fp32; GEMM A + W stay fp16 MFMA.
//   * R16: separate captured launches are the cheap sync primitive on MI355X
//     (cooperative grid.sync spins a device-scope hot line: ~100us/sync).
//   * R14: separate pool (fused-pool atomic flush hot-line serialized: 51us).
//   * R13: graph counts via binary search on sorted batch (0 atomics).
//   * R11: 8-aligned padded CSR; pad -> index N (zero row); uniform 8-batch
//     loop, uint4 = 8 packed u16 indices. R10: rows pre-scaled by dinv.
//   * R9: one wave per node (gather lives on TLP). R8: csr_src uint16.
//   * R7: MFMA GEMM w/ pre-packed W frags (C/D col=lane&15,row=(lane>>4)*4+reg
//     [HW-verified]). R2: 3-kernel parallel scan.
// ---------------------------------------------------------------------------

#define HID 128
#define NGRAPH 64

typedef _Float16 half8v __attribute__((ext_vector_type(8)));
typedef float floatx4 __attribute__((ext_vector_type(4)));
typedef float floatx2 __attribute__((ext_vector_type(2)));

__device__ __forceinline__ int idx_at(const void* p, long long i, int f64) {
    if (f64) return (int)((const long long*)p)[i];
    return ((const int*)p)[i];
}

// init counts/pooled + fill padded csr_src with N (zero-row index);
// block 0 also detects int64-vs-int32 edge_index (odd 32-bit words all zero).
__global__ void init_kernel(const int* __restrict__ ei, int* __restrict__ flag,
                            int* __restrict__ counts, float* __restrict__ pooled,
                            uint4* __restrict__ csr4, int N, int nCsr4) {
    int i = blockIdx.x * blockDim.x + threadIdx.x;
    int stride = gridDim.x * blockDim.x;
    if (i < N) counts[i] = 0;
    if (i < NGRAPH * HID) pooled[i] = 0.f;
    unsigned fillv = (unsigned)N | ((unsigned)N << 16);
    uint4 fv = make_uint4(fillv, fillv, fillv, fillv);
    for (int j = i; j < nCsr4; j += stride) csr4[j] = fv;
    if (blockIdx.x == 0) {
        __shared__ int cnt;
        if (threadIdx.x == 0) cnt = 0;
        __syncthreads();
        int z = 0;
        for (int k = threadIdx.x; k < 2048; k += 256)
            if (ei[2 * k + 1] == 0) z++;
        atomicAdd(&cnt, z);
        __syncthreads();
        if (threadIdx.x == 0) *flag = (cnt > 1024) ? 1 : 0;
    }
}

__global__ void hist_kernel(const void* __restrict__ ei, const int* __restrict__ flag,
                            int* __restrict__ counts, int E, int N) {
    int e = blockIdx.x * blockDim.x + threadIdx.x;
    if (e >= E) return;
    int f64 = *flag;
    int d = idx_at(ei, (long long)E + e, f64);
    if ((unsigned)d < (unsigned)N) atomicAdd(&counts[d], 1);
}

__device__ __forceinline__ int wave_incl_scan(int v, int lane) {
#pragma unroll
    for (int off = 1; off < 64; off <<= 1) {
        int u = __shfl_up(v, off);
        if (lane >= off) v += u;
    }
    return v;
}

// ---- 3-kernel parallel exclusive scan over PADDED counts (R2/R11) ----
__global__ __launch_bounds__(256) void blocksum_kernel(const int* __restrict__ counts,
                                                       int* __restrict__ bsums, int N) {
    int i = blockIdx.x * 256 + threadIdx.x;
    int v = (i < N) ? ((counts[i] + 7) & ~7) : 0;  // padded to 8
    int lane = threadIdx.x & 63, w = threadIdx.x >> 6;
#pragma unroll
    for (int off = 32; off > 0; off >>= 1) v += __shfl_down(v, off);
    __shared__ int ws[4];
    if (lane == 0) ws[w] = v;
    __syncthreads();
    if (threadIdx.x == 0) bsums[blockIdx.x] = ws[0] + ws[1] + ws[2] + ws[3];
}

__global__ __launch_bounds__(256) void scanb_kernel(int* __restrict__ bsums, int nb) {
    int t = threadIdx.x;
    int lane = t & 63, w = t >> 6;
    int v = (t < nb) ? bsums[t] : 0;
    int iv = wave_incl_scan(v, lane);
    __shared__ int wsum[4];
    if (lane == 63) wsum[w] = iv;
    __syncthreads();
    int add = 0;
    for (int k = 0; k < w; ++k) add += wsum[k];
    if (t < nb) bsums[t] = iv - v + add;  // exclusive
}

__global__ __launch_bounds__(256) void fill_kernel(const int* __restrict__ counts,
                                                   const int* __restrict__ bsums,
                                                   int* __restrict__ rowstart,
                                                   int* __restrict__ cursor,
                                                   float* __restrict__ dinv, int N) {
    int i = blockIdx.x * 256 + threadIdx.x;
    int c = (i < N) ? counts[i] : 0;
    int cp = (c + 7) & ~7;                        // padded
    int lane = threadIdx.x & 63, w = threadIdx.x >> 6;
    int iv = wave_incl_scan(cp, lane);
    __shared__ int wsum[4];
    if (lane == 63) wsum[w] = iv;
    __syncthreads();
    int add = bsums[blockIdx.x];
    for (int k = 0; k < w; ++k) add += wsum[k];
    int excl = iv - cp + add;
    if (i < N) {
        rowstart[i] = excl;
        cursor[i] = excl;
        dinv[i] = rsqrtf((float)(c + 1));
        if (i == N - 1) rowstart[N] = excl + cp;
    }
}

// R5: stores ONLY csr_src; R8: uint16 (requires N < 65536; here N=50000)
__global__ void scatter_kernel(const void* __restrict__ ei, const int* __restrict__ flag,
                               int* __restrict__ cursor,
                               unsigned short* __restrict__ csr_src, int E, int N) {
    int e = blockIdx.x * blockDim.x + threadIdx.x;
    if (e >= E) return;
    int f64 = *flag;
    int s = idx_at(ei, e, f64);
    int d = idx_at(ei, (long long)E + e, f64);
    if ((unsigned)s >= (unsigned)N || (unsigned)d >= (unsigned)N) return;
    int pos = atomicAdd(&cursor[d], 1);
    csr_src[pos] = (unsigned short)s;
}

// prep: blocks [0,24): pack 3x W into fragment-ordered fp16;
// block 24: zero row N of xs/hsA/hsB (fp8 rows, 32 uints each);
// blocks [25,..): xs = fp8(dinv * x) (pre-scaled layer-1 gather source, R17).
__global__ __launch_bounds__(256) void prep_kernel(const float* __restrict__ x,
                                                   const float* __restrict__ dinv,
                                                   unsigned short* __restrict__ xs8,
                                                   unsigned short* __restrict__ hsA8,
                                                   unsigned short* __restrict__ hsB8,
                                                   const float* __restrict__ W1,
                                                   const float* __restrict__ W2,
                                                   const float* __restrict__ W3,
                                                   half8v* __restrict__ wf,
                                                   int N, int n2) {
    if (blockIdx.x < 24) {
        int which = blockIdx.x >> 3;
        const float* W = which == 0 ? W1 : (which == 1 ? W2 : W3);
        int t = (blockIdx.x & 7) * 256 + threadIdx.x;  // 0..2047
        int lane = t & 63;
        int nt = (t >> 6) & 7;
        int kblk = t >> 9;
        int n = nt * 16 + (lane & 15);
        int kbase = kblk * 32 + (lane >> 4) * 8;
        half8v v;
#pragma unroll
        for (int j = 0; j < 8; ++j) v[j] = (_Float16)W[(size_t)(kbase + j) * 128 + n];
        wf[which * 2048 + t] = v;
    } else if (blockIdx.x == 24) {
        // zero row N of the three fp8 gather sources (64 ushort each)
        int t = threadIdx.x;
        if (t < 64) xs8[(size_t)N * 64 + t] = 0;
        else if (t < 128) hsA8[(size_t)N * 64 + (t - 64)] = 0;
        else if (t < 192) hsB8[(size_t)N * 64 + (t - 128)] = 0;
    } else {
        int i = (blockIdx.x - 25) * 256 + threadIdx.x;
        if (i >= n2) return;
        float dv = dinv[i >> 6];
        float2 v = ((const float2*)x)[i];
        unsigned p = __builtin_amdgcn_cvt_pk_fp8_f32(dv * v.x, dv * v.y, 0, false);
        xs8[i] = (unsigned short)p;
    }
}

// agg[i] = dinv[i] * ( xs[i] + sum_e xs[src_e] )   (rows pre-scaled, R10)
// ONE WAVE PER NODE. R17: fp8 rows (128B; ushort/lane, HW decode to float2).
// R11: padded CSR -> single uniform 8-batch loop; pads hit zero row.
__global__ __launch_bounds__(256) void agg_kernel(const unsigned short* __restrict__ xs8,
                                                  const int* __restrict__ rowstart,
                                                  const unsigned short* __restrict__ csr_src,
                                                  const float* __restrict__ dinv,
                                                  __half2* __restrict__ out, int N) {
    int wid = (blockIdx.x * blockDim.x + threadIdx.x) >> 6;
    int lane = threadIdx.x & 63;
    if (wid >= N) return;
    float di = dinv[wid];
    floatx2 s0 = __builtin_amdgcn_cvt_pk_f32_fp8((int)xs8[(size_t)wid * 64 + lane], false);
    float accx = s0[0], accy = s0[1];
    float bccx = 0.f, bccy = 0.f;
    int e0 = rowstart[wid], e1 = rowstart[wid + 1];
    for (int e = e0; e < e1; e += 8) {
        uint4 q = *(const uint4*)(csr_src + e);   // 8 packed uint16 indices
        int s0i = q.x & 0xffff, s1i = q.x >> 16;
        int s2i = q.y & 0xffff, s3i = q.y >> 16;
        int s4i = q.z & 0xffff, s5i = q.z >> 16;
        int s6i = q.w & 0xffff, s7i = q.w >> 16;
        unsigned short r0 = xs8[(size_t)s0i * 64 + lane];
        unsigned short r1 = xs8[(size_t)s1i * 64 + lane];
        unsigned short r2 = xs8[(size_t)s2i * 64 + lane];
        unsigned short r3 = xs8[(size_t)s3i * 64 + lane];
        unsigned short r4 = xs8[(size_t)s4i * 64 + lane];
        unsigned short r5 = xs8[(size_t)s5i * 64 + lane];
        unsigned short r6 = xs8[(size_t)s6i * 64 + lane];
        unsigned short r7 = xs8[(size_t)s7i * 64 + lane];
        floatx2 f0 = __builtin_amdgcn_cvt_pk_f32_fp8((int)r0, false);
        floatx2 f1 = __builtin_amdgcn_cvt_pk_f32_fp8((int)r1, false);
        floatx2 f2 = __builtin_amdgcn_cvt_pk_f32_fp8((int)r2, false);
        floatx2 f3 = __builtin_amdgcn_cvt_pk_f32_fp8((int)r3, false);
        floatx2 f4 = __builtin_amdgcn_cvt_pk_f32_fp8((int)r4, false);
        floatx2 f5 = __builtin_amdgcn_cvt_pk_f32_fp8((int)r5, false);
        floatx2 f6 = __builtin_amdgcn_cvt_pk_f32_fp8((int)r6, false);
        floatx2 f7 = __builtin_amdgcn_cvt_pk_f32_fp8((int)r7, false);
        accx += f0[0] + f2[0]; accy += f0[1] + f2[1];
        bccx += f1[0] + f3[0]; bccy += f1[1] + f3[1];
        accx += f4[0] + f6[0]; accy += f4[1] + f6[1];
        bccx += f5[0] + f7[0]; bccy += f5[1] + f7[1];
    }
    out[(size_t)wid * 64 + lane] = __floats2half2_rn(di * (accx + bccx),
                                                     di * (accy + bccy));
}

// h = relu(A @ W + b) via v_mfma_f32_16x16x32_f16. A:[M][128] fp16, W frags
// L2-resident. Wave owns 16 rows x 128 cols (32 MFMAs).
// FP8OUT (layers 1,2): O8 = fp8(dinv*relu(...)) — adjacent cols live in
// adjacent lanes; pair via shfl_xor(1), even lane packs+stores ushort.
// !FP8OUT (layer 3): fp16 plain relu for pooling.
template <bool FP8OUT>
__global__ __launch_bounds__(256) void gemm_mfma(const __half2* __restrict__ A16,
                                                 const half8v* __restrict__ wf,
                                                 const float* __restrict__ bias,
                                                 const float* __restrict__ dinv,
                                                 unsigned short* __restrict__ O8,
                                                 __half2* __restrict__ O16, int M) {
    int wid = threadIdx.x >> 6, lane = threadIdx.x & 63;
    int rowTile = blockIdx.x * 64 + wid * 16;
    int hi = lane >> 4;
    int arow = rowTile + (lane & 15);
    if (arow >= M) arow = M - 1;  // clamp; outputs guarded below
    const half8v* Arow = (const half8v*)((const _Float16*)A16 + (size_t)arow * 128);

    floatx4 acc[8];
#pragma unroll
    for (int nt = 0; nt < 8; ++nt) acc[nt] = (floatx4){0.f, 0.f, 0.f, 0.f};

#pragma unroll
    for (int kb = 0; kb < 4; ++kb) {
        half8v a = Arow[kb * 4 + hi];
#pragma unroll
        for (int nt = 0; nt < 8; ++nt) {
            half8v w = wf[(kb * 8 + nt) * 64 + lane];
            acc[nt] = __builtin_amdgcn_mfma_f32_16x16x32_f16(a, w, acc[nt], 0, 0, 0);
        }
    }

    // C/D: col = lane&15, row = (lane>>4)*4 + reg   [HW-verified]
    int ocol_lo = lane & 15;
    int orow0 = rowTile + hi * 4;
    float dv[4];
#pragma unroll
    for (int r = 0; r < 4; ++r) {
        int orow = orow0 + r;
        dv[r] = (FP8OUT && orow < M) ? dinv[orow] : 1.0f;
    }
#pragma unroll
    for (int nt = 0; nt < 8; ++nt) {
        int col = nt * 16 + ocol_lo;
        float b = bias[col];
#pragma unroll
        for (int r = 0; r < 4; ++r) {
            int orow = orow0 + r;
            float v = fmaxf(acc[nt][r] + b, 0.f);
            if (FP8OUT) {
                v *= dv[r];
                float vp = __shfl_xor(v, 1);   // partner col (all lanes exec)
                if (!(lane & 1) && orow < M) {
                    unsigned p = __builtin_amdgcn_cvt_pk_fp8_f32(v, vp, 0, false);
                    O8[(size_t)orow * 64 + (col >> 1)] = (unsigned short)p;
                }
            } else {
                if (orow < M)
                    ((_Float16*)O16)[(size_t)orow * 128 + col] = (_Float16)v;
            }
        }
    }
}

// batch is sorted: one WAVE per 8-node chunk, half2/lane (128 features),
// fp32 accumulate, atomic flush at graph boundaries. Sums only — counts via
// binary search in final (R13).
#define POOL_CHUNK 8
__global__ __launch_bounds__(256) void pool_kernel(const __half2* __restrict__ h,
                                                   const void* __restrict__ batch,
                                                   const int* __restrict__ flag,
                                                   float* __restrict__ pooled, int N) {
    int wid = (blockIdx.x * blockDim.x + threadIdx.x) >> 6;
    int lane = threadIdx.x & 63;
    int n0 = wid * POOL_CHUNK;
    if (n0 >= N) return;
    int n1 = n0 + POOL_CHUNK; if (n1 > N) n1 = N;
    int f64 = *flag;
    int g = idx_at(batch, n0, f64);
    float ax = 0.f, ay = 0.f;
    for (int n = n0; n < n1; ++n) {
        int gn = idx_at(batch, n, f64);
        if (gn != g) {
            if ((unsigned)g < (unsigned)NGRAPH) {
                atomicAdd(&pooled[g * HID + 2 * lane], ax);
                atomicAdd(&pooled[g * HID + 2 * lane + 1], ay);
            }
            ax = ay = 0.f; g = gn;
        }
        float2 v = __half22float2(h[(size_t)n * 64 + lane]);
        ax += v.x; ay += v.y;
    }
    if ((unsigned)g < (unsigned)NGRAPH) {
        atomicAdd(&pooled[g * HID + 2 * lane], ax);
        atomicAdd(&pooled[g * HID + 2 * lane + 1], ay);
    }
}

// R13: per-graph node count via binary search on sorted batch (no atomics).
__global__ __launch_bounds__(128) void final_kernel(const float* __restrict__ pooled,
                                                    const void* __restrict__ batch,
                                                    const int* __restrict__ flag,
                                                    const float* __restrict__ Wl,
                                                    const float* __restrict__ bl,
                                                    float* __restrict__ out, int N) {
    int o = blockIdx.x * blockDim.x + threadIdx.x;
    if (o >= NGRAPH * 10) return;
    int g = o / 10, c = o % 10;
    int f64 = *flag;
    auto lb = [&](int val) {
        int lo = 0, hi = N;
        while (lo < hi) {
            int mid = (lo + hi) >> 1;
            if (idx_at(batch, mid, f64) < val) lo = mid + 1; else hi = mid;
        }
        return lo;
    };
    int cnt = lb(g + 1) - lb(g);
    float inv = 1.0f / fmaxf((float)cnt, 1.0f);
    float acc = 0.f;
    for (int k = 0; k < HID; ++k)
        acc = fmaf(pooled[g * HID + k], Wl[k * 10 + c], acc);
    out[o] = acc * inv + bl[c];
}

extern "C" void kernel_launch(void* const* d_in, const int* in_sizes, int n_in,
                              void* d_out, int out_size, void* d_ws, size_t ws_size,
                              hipStream_t stream) {
    const float* x   = (const float*)d_in[0];
    const void* ei   = d_in[1];
    const void* bat  = d_in[2];
    const float* W1  = (const float*)d_in[3];
    const float* b1  = (const float*)d_in[4];
    const float* W2  = (const float*)d_in[5];
    const float* b2  = (const float*)d_in[6];
    const float* W3  = (const float*)d_in[7];
    const float* b3  = (const float*)d_in[8];
    const float* Wl  = (const float*)d_in[9];
    const float* bl  = (const float*)d_in[10];
    float* out = (float*)d_out;

    const int N = in_sizes[0] / HID;   // 50000 (< 65536: csr_src is uint16)
    const int E = in_sizes[1] / 2;     // 600000
    const int EPAD = (E + 7 * N + 7) & ~7;   // padded-CSR capacity

    char* w = (char*)d_ws;
    size_t off = 0;
    auto carve = [&](size_t bytes) -> void* {
        void* p = w + off;
        off = (off + bytes + 255) & ~(size_t)255;
        return p;
    };
    unsigned short* xs8  = (unsigned short*)carve((size_t)(N + 1) * HID); // fp8 dinv*x (+zero)
    unsigned short* hsA8 = (unsigned short*)carve((size_t)(N + 1) * HID); // fp8 dinv*h1 (+zero)
    unsigned short* hsB8 = (unsigned short*)carve((size_t)(N + 1) * HID); // fp8 dinv*h2 (+zero)
    __half2* aggB16   = (__half2*)carve((size_t)N * HID * 2);       // agg out (GEMM A, fp16)
    __half2* h3_16    = (__half2*)carve((size_t)N * HID * 2);       // h3 fp16 (pool src)
    int*     counts   = (int*)carve((size_t)N * 4);
    int*     rowstart = (int*)carve((size_t)(N + 1) * 4);
    int*     cursor   = (int*)carve((size_t)N * 4);
    float*   dinv     = (float*)carve((size_t)N * 4);
    unsigned short* csr_src = (unsigned short*)carve((size_t)EPAD * 2);
    float*   pooled   = (float*)carve((size_t)NGRAPH * HID * 4);
    half8v*  wf       = (half8v*)carve(3 * 2048 * 16);              // 3 packed W
    int*     bsums    = (int*)carve(1024);
    int*     flag     = (int*)carve(256);

    const int nb = (N + 255) / 256;
    const int n2 = N * HID / 2;

    // graph preprocessing (once; shared by all 3 layers)
    init_kernel<<<nb, 256, 0, stream>>>((const int*)ei, flag, counts, pooled,
                                        (uint4*)csr_src, N, EPAD / 8);
    hist_kernel<<<(E + 255) / 256, 256, 0, stream>>>(ei, flag, counts, E, N);
    blocksum_kernel<<<nb, 256, 0, stream>>>(counts, bsums, N);
    scanb_kernel<<<1, 256, 0, stream>>>(bsums, nb);
    fill_kernel<<<nb, 256, 0, stream>>>(counts, bsums, rowstart, cursor, dinv, N);
    scatter_kernel<<<(E + 255) / 256, 256, 0, stream>>>(ei, flag, cursor, csr_src, E, N);
    prep_kernel<<<25 + (n2 + 255) / 256, 256, 0, stream>>>(x, dinv, xs8, hsA8, hsB8,
                                                           W1, W2, W3, wf, N, n2);

    int aggBlocks  = (N + 3) / 4;        // one wave per node, 4 waves/block
    int gemmBlocks = (N + 63) / 64;      // 64 rows/block (4 waves x 16 rows)

    // layer 1
    agg_kernel<<<aggBlocks, 256, 0, stream>>>(xs8, rowstart, csr_src, dinv, aggB16, N);
    gemm_mfma<true><<<gemmBlocks, 256, 0, stream>>>(aggB16, wf, b1, dinv,
                                                    hsA8, nullptr, N);
    // layer 2
    agg_kernel<<<aggBlocks, 256, 0, stream>>>(hsA8, rowstart, csr_src, dinv, aggB16, N);
    gemm_mfma<true><<<gemmBlocks, 256, 0, stream>>>(aggB16, wf + 2048, b2, dinv,
                                                    hsB8, nullptr, N);
    // layer 3 (fp16 plain relu h3 for pooling)
    agg_kernel<<<aggBlocks, 256, 0, stream>>>(hsB8, rowstart, csr_src, dinv, aggB16, N);
    gemm_mfma<false><<<gemmBlocks, 256, 0, stream>>>(aggB16, wf + 4096, b3, dinv,
                                                     nullptr, h3_16, N);

    // mean pool (fp16 h3) + final linear (binary-searched counts)
    int poolWaves = (N + POOL_CHUNK - 1) / POOL_CHUNK;
    int poolBlocks = (poolWaves + 3) / 4;
    pool_kernel<<<poolBlocks, 256, 0, stream>>>(h3_16, bat, flag, pooled, N);
    final_kernel<<<5, 128, 0, stream>>>(pooled, bat, flag, Wl, bl, out, N);
}